// Round 13
// baseline (113.443 us; speedup 1.0000x reference)
//
#include <hip/hip_runtime.h>
#include <hip/hip_bf16.h>

// Problem constants
#define BB    16
#define CREF  256
#define CINC  256
#define COUTC 256
#define KKN   4
#define HH    56
#define WWW   56
#define HIDDEN 65
#define NPIX  3136          // 56*56
#define PPIX  3364          // 58*58 padded
#define TEMP  34.0f

typedef __bf16 bf16x8 __attribute__((ext_vector_type(8)));
typedef float  f32x4  __attribute__((ext_vector_type(4)));
typedef float  f32x16 __attribute__((ext_vector_type(16)));

// ---------------- ws layout (bytes) ----------------
#define WS_ATTN   0
#define WS_AGGB   4096
#define WS_POOL   24576
#define WS_AGGW   65536      // 16*2*8*36864 elems bf16 = 18,874,368 B  [b][ch][cb8][tap][cing][cout128][cin8]
#define WS_XPAD   19005440   // 16*3364*256*2 = 27,557,888 (+slack for staging overread)

#define ABUF  73728          // bytes per (b,ch,cb8) A slab: [tap9][cing4][cout128][16B]
#define XB_SZ 24576          // one X buffer: [cg4][row6][col64][16B]
#define ASLOT 8192           // one tap's A slab in LDS
#define LDS_TOT (2*XB_SZ + 4*ASLOT)   // 81,920 B -> 2 blocks/CU

// ---------- 1. adaptive avg pool (one wave per (b,c)) + xpad border zeroing ----------
__global__ void pool_k(const float* __restrict__ ref, float* __restrict__ pooled,
                       __bf16* __restrict__ xpad) {
    int wid = threadIdx.x >> 6, lane = threadIdx.x & 63;
    int gw = blockIdx.x * 4 + wid;            // 0..4095 = b*256+c
    const float4* r4 = reinterpret_cast<const float4*>(ref) + (size_t)gw * 784;
    float s = 0.f;
    for (int i = lane; i < 784; i += 64) {
        float4 v = r4[i];
        s += v.x + v.y + v.z + v.w;
    }
    for (int o = 32; o; o >>= 1) s += __shfl_xor(s, o);
    if (lane == 0) pooled[gw] = s * (1.0f / (float)NPIX);

    // border zeroing: 16 b * 228 border positions, 512B rows
    if (gw < 3648) {
        int b = gw / 228, i = gw % 228;
        int ph, pw;
        if (i < 58)       { ph = 0;        pw = i; }
        else if (i < 116) { ph = 57;       pw = i - 58; }
        else if (i < 172) { ph = i - 115;  pw = 0; }
        else              { ph = i - 171;  pw = 57; }
        uint2* dst = (uint2*)(xpad + ((size_t)b * PPIX + ph * 58 + pw) * 256);
        dst[lane] = (uint2){0u, 0u};
    }
}

// ---------- 2. attention + agg bias: one block per batch sample ----------
__global__ void attn_k(const float* __restrict__ pooled, const float* __restrict__ fc1w,
                       const float* __restrict__ fc2w, const float* __restrict__ fc2b,
                       const float* __restrict__ bias,
                       float* __restrict__ attn, float* __restrict__ aggb) {
    int b = blockIdx.x;
    int t = threadIdx.x;
    __shared__ float sh[HIDDEN + 7];
    __shared__ float sl[KKN];
    __shared__ float sa[KKN];
    const float* prow = pooled + b * CREF;
    {
        int j = t >> 2, sub = t & 3;
        const float4* w4 = (const float4*)(fc1w + j * CREF + sub * 64);
        const float4* p4 = (const float4*)(prow + sub * 64);
        float s = 0.f;
#pragma unroll
        for (int k = 0; k < 16; ++k) {
            float4 w = w4[k], p = p4[k];
            s += w.x * p.x + w.y * p.y + w.z * p.z + w.w * p.w;
        }
        s += __shfl_xor(s, 1); s += __shfl_xor(s, 2);
        if (sub == 0) sh[j] = fmaxf(s, 0.f);
    }
    if (t < 4) {   // j = 64
        const float4* w4 = (const float4*)(fc1w + 64 * CREF + t * 64);
        const float4* p4 = (const float4*)(prow + t * 64);
        float s = 0.f;
#pragma unroll
        for (int k = 0; k < 16; ++k) {
            float4 w = w4[k], p = p4[k];
            s += w.x * p.x + w.y * p.y + w.z * p.z + w.w * p.w;
        }
        s += __shfl_xor(s, 1); s += __shfl_xor(s, 2);
        if (t == 0) sh[64] = fmaxf(s, 0.f);
    }
    __syncthreads();
    if (t < KKN) {
        float s = fc2b[t];
        for (int j = 0; j < HIDDEN; ++j) s += sh[j] * fc2w[t * HIDDEN + j];
        sl[t] = s * (1.0f / TEMP);
    }
    __syncthreads();
    if (t == 0) {
        float m = fmaxf(fmaxf(sl[0], sl[1]), fmaxf(sl[2], sl[3]));
        float e0 = expf(sl[0] - m), e1 = expf(sl[1] - m);
        float e2 = expf(sl[2] - m), e3 = expf(sl[3] - m);
        float inv = 1.f / (e0 + e1 + e2 + e3);
        sa[0] = e0 * inv; sa[1] = e1 * inv; sa[2] = e2 * inv; sa[3] = e3 * inv;
        attn[b * 4 + 0] = sa[0]; attn[b * 4 + 1] = sa[1];
        attn[b * 4 + 2] = sa[2]; attn[b * 4 + 3] = sa[3];
    }
    __syncthreads();
    {
        float s = 0.f;
#pragma unroll
        for (int k = 0; k < KKN; ++k) s += sa[k] * bias[k * COUTC + t];
        aggb[b * COUTC + t] = s;
    }
}

// ---------- 3. blend weights -> bf16 [b][ch][cb8][tap][cing][cout128][cin8] ----------
// grid (32 cout-blocks, 8 cb8), block 256 = (cout 8) x (cr 32)
__global__ void aggw_k(const float* __restrict__ attn, const float* __restrict__ weight,
                       __bf16* __restrict__ aggw) {
    __shared__ float s_attn[64];
    int t = threadIdx.x;
    int co = t >> 5, cr = t & 31;
    int cout = blockIdx.x * 8 + co;       // 0..255
    int cb8 = blockIdx.y;                 // 0..7
    int cin = cb8 * 32 + cr;
    if (t < 64) s_attn[t] = attn[t];
    __syncthreads();
    float w[4][9];
#pragma unroll
    for (int k = 0; k < 4; ++k) {
        const float* wp = weight + ((size_t)(k * 256 + cout) * 256 + cin) * 9;
#pragma unroll
        for (int tp = 0; tp < 9; ++tp) w[k][tp] = wp[tp];
    }
    int ch = cout >> 7, coutl = cout & 127;
    int cing = cr >> 3, cinr = cr & 7;
    for (int b = 0; b < BB; ++b) {
        float a0 = s_attn[b * 4 + 0], a1 = s_attn[b * 4 + 1];
        float a2 = s_attn[b * 4 + 2], a3 = s_attn[b * 4 + 3];
#pragma unroll
        for (int tap = 0; tap < 9; ++tap) {
            float v = a0 * w[0][tap] + a1 * w[1][tap] + a2 * w[2][tap] + a3 * w[3][tap];
            size_t e = (size_t)((b * 2 + ch) * 8 + cb8) * 36864 +
                       (tap * 4 + cing) * 1024 + coutl * 8 + cinr;
            aggw[e] = (__bf16)v;
        }
    }
}

// ---------- 4. x -> padded NHWC bf16 (interior, tiled transpose) ----------
__global__ void xpad_int_k(const float* __restrict__ x, __bf16* __restrict__ xpad) {
    __shared__ float tile[64][65];
    int pt = blockIdx.x;      // 0..48 pixel tile (64 px)
    int cg = blockIdx.y;      // 0..3 cin group (64 cins)
    int b  = blockIdx.z;
    int q = threadIdx.x >> 6, l = threadIdx.x & 63;
    for (int k = 0; k < 16; ++k) {
        int cl = q * 16 + k;
        tile[cl][l] = x[((size_t)(b * 256 + cg * 64 + cl)) * NPIX + pt * 64 + l];
    }
    __syncthreads();
    for (int k = 0; k < 16; ++k) {
        int pl = q * 16 + k;
        int pixel = pt * 64 + pl;
        int h = pixel / 56, w = pixel - h * 56;
        xpad[(((size_t)b * PPIX + (h + 1) * 58 + (w + 1)) * 256) + cg * 64 + l] =
            (__bf16)tile[l][pl];
    }
}

// ---------- 5. conv: implicit GEMM, r11 schedule + 32x32x16 MFMA ----------
// block: 256 thr = 4 waves; wave = 128 couts x 56 px (1 row), M-tiles 4x32, N-tiles 2x32.
// grid = 16b x 14rp x 2ch = 448, XCD-swizzled. LDS 80KB -> 2 blocks/CU (anti-phase).
// Per tap: [stage issues] -> [12 direct ds_reads (A 8, B 4)] -> s_barrier(counted vmcnt)
//          -> lgkmcnt(0) -> setprio(1) 16 MFMA(32x32x16) setprio(0).
// Staging ring/ledger identical to round 11 (verified): A(g) staged tap g-3, vmcnt 4
// steady / 10 while X in flight / taper 4,2,0 at the tail.
__global__ __launch_bounds__(256, 2) void conv_k(const __bf16* __restrict__ xpad,
                                                 const __bf16* __restrict__ aggw,
                                                 const float* __restrict__ aggb,
                                                 float* __restrict__ out) {
    extern __shared__ __attribute__((aligned(16))) char smem[];
    char* xs = smem;                  // 2 x 24KB X buffers
    char* as = smem + 2 * XB_SZ;      // 4 x 8KB A ring

    const int orig = blockIdx.x;
    const int logical = (orig & 7) * 56 + (orig >> 3);   // bijective, 448 = 8*56
    const int b  = logical / 28;
    const int r  = logical - b * 28;
    const int rp = r >> 1;            // 0..13 row-quad
    const int ch = r & 1;             // cout half
    const int tid = threadIdx.x;
    const int wid = tid >> 6, lane = tid & 63;
    const int l31 = lane & 31, l5 = lane >> 5;
    const int h0 = rp * 4;            // top padded row staged (rows h0..h0+5)

    const char* xb  = (const char*)xpad + (size_t)b * PPIX * 512;
    const char* awb = (const char*)aggw + (size_t)((b * 2 + ch) * 8) * ABUF;

    f32x16 acc[4][2];                 // [m-tile][n-tile], 128 VGPR total
#pragma unroll
    for (int m = 0; m < 4; ++m)
#pragma unroll
        for (int n = 0; n < 2; ++n)
#pragma unroll
            for (int i = 0; i < 16; ++i) acc[m][n][i] = 0.f;

    bf16x8 af[2][4];     // A frags per k16-half x m-tile
    bf16x8 bfr[2][2];    // B frags per k16-half x n-tile

    // stage X K-block c into buffer buf: 24 x 1KB, wave wid does cg=wid rows 0..5
    auto XSTAGE = [&](int buf, int c) {
#pragma unroll
        for (int j = 0; j < 6; ++j) {
            const char* src = xb + (size_t)((h0 + j) * 58 + lane) * 512 + c * 64 + wid * 16;
            __builtin_amdgcn_global_load_lds(
                (const __attribute__((address_space(1))) void*)src,
                (__attribute__((address_space(3))) void*)(xs + buf * XB_SZ + (wid * 6 + j) * 1024),
                16, 0, 0);
        }
    };
    // stage one tap's 8KB A slab into ring slot: 8 x 1KB, 2 per wave
    auto ASTAGE = [&](int slot, int c, int tap) {
#pragma unroll
        for (int j = 0; j < 2; ++j) {
            int k = wid * 2 + j;
            const char* src = awb + (size_t)c * ABUF + tap * 8192 + k * 1024 + lane * 16;
            __builtin_amdgcn_global_load_lds(
                (const __attribute__((address_space(1))) void*)src,
                (__attribute__((address_space(3))) void*)(as + slot * ASLOT + k * 1024),
                16, 0, 0);
        }
    };

// A frag (32x32x16): lane: m = mt*32 + l31, k = k16*16 + l5*8 + j  -> cing = k16*2+l5
#define ALOADF(SLOT) do { \
    _Pragma("unroll") \
    for (int k_ = 0; k_ < 2; ++k_) { \
        const char* ap_ = as + (SLOT) * ASLOT + (k_ * 2 + l5) * 2048 + l31 * 16; \
        _Pragma("unroll") \
        for (int m_ = 0; m_ < 4; ++m_) af[k_][m_] = *(const bf16x8*)(ap_ + m_ * 512); \
    } \
} while (0)

// B frag: lane: n(px) = nt*32 + l31, k -> cg = k16*2+l5; row = wid+kh, col = px+kw
#define BLOADF(T, LB) do { \
    const int kh_ = (T) / 3, kw_ = (T) - kh_ * 3; \
    _Pragma("unroll") \
    for (int k_ = 0; k_ < 2; ++k_) \
        _Pragma("unroll") \
        for (int n_ = 0; n_ < 2; ++n_) \
            bfr[k_][n_] = *(const bf16x8*)((LB) + \
                ((((k_ * 2 + l5) * 6 + wid + kh_) * 64) + n_ * 32 + l31 + kw_) * 16); \
} while (0)

#define MFMAS() do { \
    __builtin_amdgcn_s_setprio(1); \
    _Pragma("unroll") \
    for (int k_ = 0; k_ < 2; ++k_) \
        _Pragma("unroll") \
        for (int n_ = 0; n_ < 2; ++n_) \
            _Pragma("unroll") \
            for (int m_ = 0; m_ < 4; ++m_) \
                acc[m_][n_] = __builtin_amdgcn_mfma_f32_32x32x16_bf16( \
                    af[k_][m_], bfr[k_][n_], acc[m_][n_], 0, 0, 0); \
    __builtin_amdgcn_s_setprio(0); \
} while (0)

#define SUBBAR(N) do { \
        asm volatile("s_waitcnt vmcnt(" #N ")" ::: "memory"); \
        __builtin_amdgcn_s_barrier(); \
        __builtin_amdgcn_sched_barrier(0); } while (0)

#define LGKM0 do { \
        asm volatile("s_waitcnt lgkmcnt(0)" ::: "memory"); \
        __builtin_amdgcn_sched_barrier(0); } while (0)

    // prologue: X(0); A taps 0,1,2 -> slots 0,1,2; full drain once
    XSTAGE(0, 0);
    ASTAGE(0, 0, 0);
    ASTAGE(1, 0, 1);
    ASTAGE(2, 0, 2);
    SUBBAR(0);

    int cur = 0;
    for (int c = 0; c < 8; ++c) {
        const int cs = c & 3;
        const char* lb = xs + cur * XB_SZ;
#pragma unroll
        for (int t = 0; t < 9; ++t) {
            // ---- stage issues (A for global tap g+3; X at t==5) ----
            if (c < 7) {
                if (t < 6) ASTAGE((t + cs + 3) & 3, c, t + 3);
                else       ASTAGE((t + cs + 3) & 3, c + 1, t - 6);
                if (t == 5) XSTAGE(cur ^ 1, c + 1);
            } else {
                if (t < 6) ASTAGE((t + cs + 3) & 3, 7, t + 3);
            }
            // ---- direct fragment reads for THIS tap ----
            ALOADF((t + cs) & 3);
            BLOADF(t, lb);
            // ---- barrier with counted vmcnt (per-wave FIFO ledger, r11-verified) ----
            if (c < 7) {
                if (t <= 4 || t == 8) SUBBAR(4); else SUBBAR(10);
            } else {
                if (t <= 5)      { SUBBAR(4); }
                else if (t == 6) { SUBBAR(2); }
                else if (t == 7) { SUBBAR(0); }
                // t == 8: no barrier needed (epilogue follows)
            }
            LGKM0;
            MFMAS();
        }
        cur ^= 1;
    }
#undef ALOADF
#undef BLOADF
#undef MFMAS
#undef SUBBAR
#undef LGKM0

    // epilogue: D layout (32x32): px = l31 (col), crow = (reg&3) + 8*(reg>>2) + 4*l5
    const int row = rp * 4 + wid;             // output row
#pragma unroll
    for (int mt = 0; mt < 4; ++mt) {
#pragma unroll
        for (int q = 0; q < 4; ++q) {
#pragma unroll
            for (int i = 0; i < 4; ++i) {
                int crow = i + q * 8 + 4 * l5;
                int cout = ch * 128 + mt * 32 + crow;
                float bv = aggb[b * COUTC + cout];
                float* op = out + ((size_t)(b * COUTC + cout) * NPIX + row * 56);
                __builtin_nontemporal_store(acc[mt][0][q * 4 + i] + bv, op + l31);
                if (l31 < 24)
                    __builtin_nontemporal_store(acc[mt][1][q * 4 + i] + bv, op + 32 + l31);
            }
        }
    }
}

extern "C" void kernel_launch(void* const* d_in, const int* in_sizes, int n_in,
                              void* d_out, int out_size, void* d_ws, size_t ws_size,
                              hipStream_t stream) {
    (void)in_sizes; (void)n_in; (void)out_size; (void)ws_size;
    const float* ref    = (const float*)d_in[0];
    const float* x      = (const float*)d_in[1];
    const float* fc1w   = (const float*)d_in[2];
    const float* fc2w   = (const float*)d_in[3];
    const float* fc2b   = (const float*)d_in[4];
    const float* weight = (const float*)d_in[5];
    const float* bias   = (const float*)d_in[6];
    float* out = (float*)d_out;
    char* ws = (char*)d_ws;

    float*  attn   = (float*)(ws + WS_ATTN);
    float*  aggb   = (float*)(ws + WS_AGGB);
    float*  pooled = (float*)(ws + WS_POOL);
    __bf16* aggw   = (__bf16*)(ws + WS_AGGW);
    __bf16* xpad   = (__bf16*)(ws + WS_XPAD);

    // allow >64KB dynamic LDS for conv_k (deterministic, capture-safe host call)
    hipFuncSetAttribute((const void*)conv_k,
                        hipFuncAttributeMaxDynamicSharedMemorySize, LDS_TOT);

    pool_k<<<1024, 256, 0, stream>>>(ref, pooled, xpad);
    attn_k<<<16, 256, 0, stream>>>(pooled, fc1w, fc2w, fc2b, bias, attn, aggb);
    aggw_k<<<dim3(32, 8), 256, 0, stream>>>(attn, weight, aggw);
    xpad_int_k<<<dim3(49, 4, 16), 256, 0, stream>>>(x, xpad);
    conv_k<<<448, 256, LDS_TOT, stream>>>(xpad, aggw, aggb, out);
}

// Round 14
// 98.838 us; speedup vs baseline: 1.1478x; 1.1478x over previous
//
#include <hip/hip_runtime.h>
#include <hip/hip_bf16.h>

// Problem constants
#define BB    16
#define CREF  256
#define CINC  256
#define COUTC 256
#define KKN   4
#define HH    56
#define WWW   56
#define HIDDEN 65
#define NPIX  3136          // 56*56
#define PPIX  3364          // 58*58 padded
#define TEMP  34.0f

typedef __bf16 bf16x8 __attribute__((ext_vector_type(8)));
typedef float  f32x4  __attribute__((ext_vector_type(4)));

// ---------------- ws layout (bytes) ----------------
#define WS_ATTN   0
#define WS_AGGB   4096
#define WS_POOL   24576
#define WS_AGGW   65536      // 16*2*8*36864 elems bf16 = 18,874,368 B  [b][ch][cb8][tap][cing][cout128][cin8]
#define WS_XPAD   19005440   // 16*3364*256*2 = 27,557,888 (+slack for staging overread)

#define ABUF  73728          // bytes per (b,ch,cb8) A slab: [tap9][cing4][cout128][16B]
#define XB_SZ 24576          // one X buffer: [cg4][row6][col64][16B]
#define ASLOT 8192           // one tap's A slab in LDS
#define LDS_TOT (2*XB_SZ + 4*ASLOT)   // 81,920 B -> 2 blocks/CU

// ---------- 1. adaptive avg pool (one wave per (b,c)) + xpad border zeroing ----------
__global__ void pool_k(const float* __restrict__ ref, float* __restrict__ pooled,
                       __bf16* __restrict__ xpad) {
    int wid = threadIdx.x >> 6, lane = threadIdx.x & 63;
    int gw = blockIdx.x * 4 + wid;            // 0..4095 = b*256+c
    const float4* r4 = reinterpret_cast<const float4*>(ref) + (size_t)gw * 784;
    float s = 0.f;
    for (int i = lane; i < 784; i += 64) {
        float4 v = r4[i];
        s += v.x + v.y + v.z + v.w;
    }
    for (int o = 32; o; o >>= 1) s += __shfl_xor(s, o);
    if (lane == 0) pooled[gw] = s * (1.0f / (float)NPIX);

    // border zeroing: 16 b * 228 border positions, 512B rows
    if (gw < 3648) {
        int b = gw / 228, i = gw % 228;
        int ph, pw;
        if (i < 58)       { ph = 0;        pw = i; }
        else if (i < 116) { ph = 57;       pw = i - 58; }
        else if (i < 172) { ph = i - 115;  pw = 0; }
        else              { ph = i - 171;  pw = 57; }
        uint2* dst = (uint2*)(xpad + ((size_t)b * PPIX + ph * 58 + pw) * 256);
        dst[lane] = (uint2){0u, 0u};
    }
}

// ---------- 2. attention + agg bias: one block per batch sample ----------
__global__ void attn_k(const float* __restrict__ pooled, const float* __restrict__ fc1w,
                       const float* __restrict__ fc2w, const float* __restrict__ fc2b,
                       const float* __restrict__ bias,
                       float* __restrict__ attn, float* __restrict__ aggb) {
    int b = blockIdx.x;
    int t = threadIdx.x;
    __shared__ float sh[HIDDEN + 7];
    __shared__ float sl[KKN];
    __shared__ float sa[KKN];
    const float* prow = pooled + b * CREF;
    {
        int j = t >> 2, sub = t & 3;
        const float4* w4 = (const float4*)(fc1w + j * CREF + sub * 64);
        const float4* p4 = (const float4*)(prow + sub * 64);
        float s = 0.f;
#pragma unroll
        for (int k = 0; k < 16; ++k) {
            float4 w = w4[k], p = p4[k];
            s += w.x * p.x + w.y * p.y + w.z * p.z + w.w * p.w;
        }
        s += __shfl_xor(s, 1); s += __shfl_xor(s, 2);
        if (sub == 0) sh[j] = fmaxf(s, 0.f);
    }
    if (t < 4) {   // j = 64
        const float4* w4 = (const float4*)(fc1w + 64 * CREF + t * 64);
        const float4* p4 = (const float4*)(prow + t * 64);
        float s = 0.f;
#pragma unroll
        for (int k = 0; k < 16; ++k) {
            float4 w = w4[k], p = p4[k];
            s += w.x * p.x + w.y * p.y + w.z * p.z + w.w * p.w;
        }
        s += __shfl_xor(s, 1); s += __shfl_xor(s, 2);
        if (t == 0) sh[64] = fmaxf(s, 0.f);
    }
    __syncthreads();
    if (t < KKN) {
        float s = fc2b[t];
        for (int j = 0; j < HIDDEN; ++j) s += sh[j] * fc2w[t * HIDDEN + j];
        sl[t] = s * (1.0f / TEMP);
    }
    __syncthreads();
    if (t == 0) {
        float m = fmaxf(fmaxf(sl[0], sl[1]), fmaxf(sl[2], sl[3]));
        float e0 = expf(sl[0] - m), e1 = expf(sl[1] - m);
        float e2 = expf(sl[2] - m), e3 = expf(sl[3] - m);
        float inv = 1.f / (e0 + e1 + e2 + e3);
        sa[0] = e0 * inv; sa[1] = e1 * inv; sa[2] = e2 * inv; sa[3] = e3 * inv;
        attn[b * 4 + 0] = sa[0]; attn[b * 4 + 1] = sa[1];
        attn[b * 4 + 2] = sa[2]; attn[b * 4 + 3] = sa[3];
    }
    __syncthreads();
    {
        float s = 0.f;
#pragma unroll
        for (int k = 0; k < KKN; ++k) s += sa[k] * bias[k * COUTC + t];
        aggb[b * COUTC + t] = s;
    }
}

// ---------- 3. blend weights -> bf16 [b][ch][cb8][tap][cing][cout128][cin8] ----------
// grid (32 cout-blocks, 8 cb8), block 256 = (cout 8) x (cr 32)
__global__ void aggw_k(const float* __restrict__ attn, const float* __restrict__ weight,
                       __bf16* __restrict__ aggw) {
    __shared__ float s_attn[64];
    int t = threadIdx.x;
    int co = t >> 5, cr = t & 31;
    int cout = blockIdx.x * 8 + co;       // 0..255
    int cb8 = blockIdx.y;                 // 0..7
    int cin = cb8 * 32 + cr;
    if (t < 64) s_attn[t] = attn[t];
    __syncthreads();
    float w[4][9];
#pragma unroll
    for (int k = 0; k < 4; ++k) {
        const float* wp = weight + ((size_t)(k * 256 + cout) * 256 + cin) * 9;
#pragma unroll
        for (int tp = 0; tp < 9; ++tp) w[k][tp] = wp[tp];
    }
    int ch = cout >> 7, coutl = cout & 127;
    int cing = cr >> 3, cinr = cr & 7;
    for (int b = 0; b < BB; ++b) {
        float a0 = s_attn[b * 4 + 0], a1 = s_attn[b * 4 + 1];
        float a2 = s_attn[b * 4 + 2], a3 = s_attn[b * 4 + 3];
#pragma unroll
        for (int tap = 0; tap < 9; ++tap) {
            float v = a0 * w[0][tap] + a1 * w[1][tap] + a2 * w[2][tap] + a3 * w[3][tap];
            size_t e = (size_t)((b * 2 + ch) * 8 + cb8) * 36864 +
                       (tap * 4 + cing) * 1024 + coutl * 8 + cinr;
            aggw[e] = (__bf16)v;
        }
    }
}

// ---------- 4. x -> padded NHWC bf16 (interior, tiled transpose) ----------
__global__ void xpad_int_k(const float* __restrict__ x, __bf16* __restrict__ xpad) {
    __shared__ float tile[64][65];
    int pt = blockIdx.x;      // 0..48 pixel tile (64 px)
    int cg = blockIdx.y;      // 0..3 cin group (64 cins)
    int b  = blockIdx.z;
    int q = threadIdx.x >> 6, l = threadIdx.x & 63;
    for (int k = 0; k < 16; ++k) {
        int cl = q * 16 + k;
        tile[cl][l] = x[((size_t)(b * 256 + cg * 64 + cl)) * NPIX + pt * 64 + l];
    }
    __syncthreads();
    for (int k = 0; k < 16; ++k) {
        int pl = q * 16 + k;
        int pixel = pt * 64 + pl;
        int h = pixel / 56, w = pixel - h * 56;
        xpad[(((size_t)b * PPIX + (h + 1) * 58 + (w + 1)) * 256) + cg * 64 + l] =
            (__bf16)tile[l][pl];
    }
}

// ---------- 5. conv: implicit GEMM. X dbuf + A 4-slot tap-ring, template phase discipline ----------
// block: 256 thr = 4 waves; wave = 128 couts x 56 px (1 row), Mr=8, Nr=4.
// grid = 16b x 14rp x 2ch = 448, XCD-swizzled. LDS 80KB -> 2 blocks/CU (anti-phase overlap).
// Per tap (phase): [stage issues] -> [12 direct ds_reads] -> s_barrier(counted vmcnt)
//                  -> lgkmcnt(0) -> setprio(1) 32 MFMA setprio(0).
// Ledger: A(g) staged at global tap g-3, read at tap g start (2 barriers of slack);
// slot g%4 overwritten at tap g+3 (>=1 barrier after last read). vmcnt: 4 steady,
// 10 while X in flight (t=5..7), taper 4/2/0 in the last cb8.
__global__ __launch_bounds__(256, 2) void conv_k(const __bf16* __restrict__ xpad,
                                                 const __bf16* __restrict__ aggw,
                                                 const float* __restrict__ aggb,
                                                 float* __restrict__ out) {
    extern __shared__ __attribute__((aligned(16))) char smem[];
    char* xs = smem;                  // 2 x 24KB X buffers
    char* as = smem + 2 * XB_SZ;      // 4 x 8KB A ring

    const int orig = blockIdx.x;
    const int logical = (orig & 7) * 56 + (orig >> 3);   // bijective, 448 = 8*56
    const int b  = logical / 28;
    const int r  = logical - b * 28;
    const int rp = r >> 1;            // 0..13 row-quad
    const int ch = r & 1;             // cout half
    const int tid = threadIdx.x;
    const int wid = tid >> 6, lane = tid & 63;
    const int l15 = lane & 15, l4 = lane >> 4;
    const int h0 = rp * 4;            // top padded row staged (rows h0..h0+5)

    const char* xb  = (const char*)xpad + (size_t)b * PPIX * 512;
    const char* awb = (const char*)aggw + (size_t)((b * 2 + ch) * 8) * ABUF;

    f32x4 acc[8][4];
#pragma unroll
    for (int m = 0; m < 8; ++m)
#pragma unroll
        for (int n = 0; n < 4; ++n) acc[m][n] = (f32x4){0.f, 0.f, 0.f, 0.f};

    bf16x8 af[8];     // A fragments (direct use, single set)
    bf16x8 bfr[4];    // B fragments

    // stage X K-block c into buffer buf: 24 x 1KB, wave wid does cg=wid rows 0..5
    auto XSTAGE = [&](int buf, int c) {
#pragma unroll
        for (int j = 0; j < 6; ++j) {
            const char* src = xb + (size_t)((h0 + j) * 58 + lane) * 512 + c * 64 + wid * 16;
            __builtin_amdgcn_global_load_lds(
                (const __attribute__((address_space(1))) void*)src,
                (__attribute__((address_space(3))) void*)(xs + buf * XB_SZ + (wid * 6 + j) * 1024),
                16, 0, 0);
        }
    };
    // stage one tap's 8KB A slab into ring slot: 8 x 1KB, 2 per wave
    auto ASTAGE = [&](int slot, int c, int tap) {
#pragma unroll
        for (int j = 0; j < 2; ++j) {
            int k = wid * 2 + j;
            const char* src = awb + (size_t)c * ABUF + tap * 8192 + k * 1024 + lane * 16;
            __builtin_amdgcn_global_load_lds(
                (const __attribute__((address_space(1))) void*)src,
                (__attribute__((address_space(3))) void*)(as + slot * ASLOT + k * 1024),
                16, 0, 0);
        }
    };

#define ALOADF(SLOT) do { \
    const char* ap_ = as + (SLOT) * ASLOT + l4 * 2048 + l15 * 16; \
    _Pragma("unroll") \
    for (int m_ = 0; m_ < 8; ++m_) af[m_] = *(const bf16x8*)(ap_ + m_ * 256); \
} while (0)

#define BLOADF(T, LB) do { \
    const int kh_ = (T) / 3, kw_ = (T) - kh_ * 3; \
    _Pragma("unroll") \
    for (int nf_ = 0; nf_ < 4; ++nf_) \
        bfr[nf_] = *(const bf16x8*)((LB) + \
            (((l4 * 6 + wid + kh_) * 64) + nf_ * 16 + l15 + kw_) * 16); \
} while (0)

#define MFMAS() do { \
    __builtin_amdgcn_s_setprio(1); \
    _Pragma("unroll") \
    for (int nf_ = 0; nf_ < 4; ++nf_) \
        _Pragma("unroll") \
        for (int m_ = 0; m_ < 8; ++m_) \
            acc[m_][nf_] = __builtin_amdgcn_mfma_f32_16x16x32_bf16( \
                af[m_], bfr[nf_], acc[m_][nf_], 0, 0, 0); \
    __builtin_amdgcn_s_setprio(0); \
} while (0)

#define SUBBAR(N) do { \
        asm volatile("s_waitcnt vmcnt(" #N ")" ::: "memory"); \
        __builtin_amdgcn_s_barrier(); \
        __builtin_amdgcn_sched_barrier(0); } while (0)

#define LGKM0 do { \
        asm volatile("s_waitcnt lgkmcnt(0)" ::: "memory"); \
        __builtin_amdgcn_sched_barrier(0); } while (0)

    // prologue: X(0); A taps 0,1,2 -> slots 0,1,2; full drain once
    XSTAGE(0, 0);
    ASTAGE(0, 0, 0);
    ASTAGE(1, 0, 1);
    ASTAGE(2, 0, 2);
    SUBBAR(0);

    int cur = 0;
    for (int c = 0; c < 8; ++c) {
        const int cs = c & 3;
        const char* lb = xs + cur * XB_SZ;
#pragma unroll
        for (int t = 0; t < 9; ++t) {
            // ---- stage issues (A for global tap g+3; X at t==5) ----
            if (c < 7) {
                if (t < 6) ASTAGE((t + cs + 3) & 3, c, t + 3);
                else       ASTAGE((t + cs + 3) & 3, c + 1, t - 6);
                if (t == 5) XSTAGE(cur ^ 1, c + 1);
            } else {
                if (t < 6) ASTAGE((t + cs + 3) & 3, 7, t + 3);
            }
            // ---- direct fragment reads for THIS tap ----
            ALOADF((t + cs) & 3);
            BLOADF(t, lb);
            // ---- barrier with counted vmcnt (per-wave FIFO ledger) ----
            if (c < 7) {
                if (t <= 4 || t == 8) SUBBAR(4); else SUBBAR(10);
            } else {
                if (t <= 5)      { SUBBAR(4); }
                else if (t == 6) { SUBBAR(2); }
                else if (t == 7) { SUBBAR(0); }
                // t == 8: no barrier needed (epilogue follows)
            }
            LGKM0;
            MFMAS();
        }
        cur ^= 1;
    }
#undef ALOADF
#undef BLOADF
#undef MFMAS
#undef SUBBAR
#undef LGKM0

    const int row = rp * 4 + wid;             // output row
#pragma unroll
    for (int m = 0; m < 8; ++m) {
#pragma unroll
        for (int i = 0; i < 4; ++i) {
            int cout = ch * 128 + m * 16 + l4 * 4 + i;
            float bv = aggb[b * COUTC + cout];
            float* op = out + ((size_t)(b * COUTC + cout) * NPIX + row * 56);
#pragma unroll
            for (int nf = 0; nf < 3; ++nf)
                __builtin_nontemporal_store(acc[m][nf][i] + bv, op + nf * 16 + l15);
            if (l15 < 8)
                __builtin_nontemporal_store(acc[m][3][i] + bv, op + 48 + l15);
        }
    }
}

extern "C" void kernel_launch(void* const* d_in, const int* in_sizes, int n_in,
                              void* d_out, int out_size, void* d_ws, size_t ws_size,
                              hipStream_t stream) {
    (void)in_sizes; (void)n_in; (void)out_size; (void)ws_size;
    const float* ref    = (const float*)d_in[0];
    const float* x      = (const float*)d_in[1];
    const float* fc1w   = (const float*)d_in[2];
    const float* fc2w   = (const float*)d_in[3];
    const float* fc2b   = (const float*)d_in[4];
    const float* weight = (const float*)d_in[5];
    const float* bias   = (const float*)d_in[6];
    float* out = (float*)d_out;
    char* ws = (char*)d_ws;

    float*  attn   = (float*)(ws + WS_ATTN);
    float*  aggb   = (float*)(ws + WS_AGGB);
    float*  pooled = (float*)(ws + WS_POOL);
    __bf16* aggw   = (__bf16*)(ws + WS_AGGW);
    __bf16* xpad   = (__bf16*)(ws + WS_XPAD);

    // allow >64KB dynamic LDS for conv_k (deterministic, capture-safe host call)
    hipFuncSetAttribute((const void*)conv_k,
                        hipFuncAttributeMaxDynamicSharedMemorySize, LDS_TOT);

    pool_k<<<1024, 256, 0, stream>>>(ref, pooled, xpad);
    attn_k<<<16, 256, 0, stream>>>(pooled, fc1w, fc2w, fc2b, bias, attn, aggb);
    aggw_k<<<dim3(32, 8), 256, 0, stream>>>(attn, weight, aggw);
    xpad_int_k<<<dim3(49, 4, 16), 256, 0, stream>>>(x, xpad);
    conv_k<<<448, 256, LDS_TOT, stream>>>(xpad, aggw, aggb, out);
}